// Round 3
// baseline (9865.171 us; speedup 1.0000x reference)
//
#include <hip/hip_runtime.h>
#include <cstddef>
#include <cmath>

#define BATCH 64
#define NPTS  256
#define DIM   512

// ---------------- norms: out[r] = sum(x[r][:]^2), one wave per row ----------------
__global__ __launch_bounds__(256) void norms_kernel(const float* __restrict__ x,
                                                    float* __restrict__ out) {
  const int w = threadIdx.x >> 6, lane = threadIdx.x & 63;
  const int r = blockIdx.x * 4 + w;            // 4 waves/block, 1 row/wave
  const float4* row = reinterpret_cast<const float4*>(x + (size_t)r * DIM);
  float4 v0 = row[lane];
  float4 v1 = row[lane + 64];
  float s = v0.x*v0.x + v0.y*v0.y + v0.z*v0.z + v0.w*v0.w
          + v1.x*v1.x + v1.y*v1.y + v1.z*v1.z + v1.w*v1.w;
#pragma unroll
  for (int off = 32; off; off >>= 1) s += __shfl_xor(s, off);
  if (lane == 0) out[r] = s;
}

// ---------------- cost[b][j][i] = sqrt(max(sq2[j]+sq1[i]-2*<seq2_j,seq1_i>,0)) ----------------
#define BM 64
#define BN 64
#define BK 32
__global__ __launch_bounds__(256) void cost_kernel(const float* __restrict__ seq1,
                                                   const float* __restrict__ seq2,
                                                   const float* __restrict__ sq1,
                                                   const float* __restrict__ sq2,
                                                   float* __restrict__ cost) {
  const int b  = blockIdx.z;
  const int j0 = blockIdx.y * BM;   // rows  (seq2 index j)
  const int i0 = blockIdx.x * BN;   // cols  (seq1 index i)
  const int t  = threadIdx.x;
  const int tx = t & 15, ty = t >> 4;

  __shared__ float As[BK][BM + 1];  // seq2 tile, k-major
  __shared__ float Bs[BK][BN + 1];  // seq1 tile, k-major

  const float* A  = seq2 + ((size_t)b * NPTS + j0) * DIM;
  const float* Bp = seq1 + ((size_t)b * NPTS + i0) * DIM;

  float acc[4][4] = {};

  for (int k0 = 0; k0 < DIM; k0 += BK) {
#pragma unroll
    for (int l = 0; l < 2; ++l) {
      int f  = t + l * 256;           // 512 float4 loads per tile pair
      int r  = f >> 3;                // 0..63
      int c4 = (f & 7) * 4;           // 0..28
      float4 a  = *reinterpret_cast<const float4*>(A  + (size_t)r * DIM + k0 + c4);
      float4 bb = *reinterpret_cast<const float4*>(Bp + (size_t)r * DIM + k0 + c4);
      As[c4 + 0][r] = a.x;  As[c4 + 1][r] = a.y;  As[c4 + 2][r] = a.z;  As[c4 + 3][r] = a.w;
      Bs[c4 + 0][r] = bb.x; Bs[c4 + 1][r] = bb.y; Bs[c4 + 2][r] = bb.z; Bs[c4 + 3][r] = bb.w;
    }
    __syncthreads();
#pragma unroll
    for (int kk = 0; kk < BK; ++kk) {
      float a[4], bb[4];
#pragma unroll
      for (int q = 0; q < 4; ++q) a[q]  = As[kk][ty * 4 + q];
#pragma unroll
      for (int q = 0; q < 4; ++q) bb[q] = Bs[kk][tx * 4 + q];
#pragma unroll
      for (int x = 0; x < 4; ++x)
#pragma unroll
        for (int y = 0; y < 4; ++y) acc[x][y] += a[x] * bb[y];
    }
    __syncthreads();
  }

#pragma unroll
  for (int x = 0; x < 4; ++x) {
    int j = j0 + ty * 4 + x;
    float s2 = sq2[b * NPTS + j];
    float4 o;
    float r0 = s2 + sq1[b * NPTS + i0 + tx * 4 + 0] - 2.f * acc[x][0];
    float r1 = s2 + sq1[b * NPTS + i0 + tx * 4 + 1] - 2.f * acc[x][1];
    float r2 = s2 + sq1[b * NPTS + i0 + tx * 4 + 2] - 2.f * acc[x][2];
    float r3 = s2 + sq1[b * NPTS + i0 + tx * 4 + 3] - 2.f * acc[x][3];
    o.x = sqrtf(fmaxf(r0, 0.f)); o.y = sqrtf(fmaxf(r1, 0.f));
    o.z = sqrtf(fmaxf(r2, 0.f)); o.w = sqrtf(fmaxf(r3, 0.f));
    *reinterpret_cast<float4*>(cost + ((size_t)b * NPTS + j) * NPTS + i0 + tx * 4) = o;
  }
}

// ---------------- Hungarian (JV) — one wave per batch problem ----------------
// Mirrors the reference exactly: u/v/minv in double (numpy float64 promotion),
// argmin tie-break = lowest column index (np.argmin).
__global__ __launch_bounds__(64) void hungarian_kernel(const float* __restrict__ cost,
                                                       int* __restrict__ col_out) {
  const int b    = blockIdx.x;
  const int lane = threadIdx.x;                 // 0..63, owns columns lane*4+1 .. lane*4+4
  const float* C = cost + (size_t)b * NPTS * NPTS;

  __shared__ double u_sh[NPTS + 1];
  __shared__ int    p_sh[NPTS + 1];
  __shared__ int    way_sh[NPTS + 1];

  double v[4]    = {0.0, 0.0, 0.0, 0.0};
  double minv[4];

  for (int t = lane; t <= NPTS; t += 64) { u_sh[t] = 0.0; p_sh[t] = 0; way_sh[t] = 0; }
  __syncthreads();

  for (int i = 1; i <= NPTS; ++i) {
    if (lane == 0) p_sh[0] = i;
    minv[0] = minv[1] = minv[2] = minv[3] = HUGE_VAL;
    unsigned usedmask = 0;
    int j0 = 0;
    int i0 = i;

    for (int it = 0; it <= NPTS; ++it) {        // bounded: each iter marks a new column
      if (j0 > 0) {
        int c = j0 - 1;
        if ((c >> 2) == lane) usedmask |= 1u << (c & 3);
      }
      double ui = u_sh[i0];
      float4 cr = *reinterpret_cast<const float4*>(C + (size_t)(i0 - 1) * NPTS + lane * 4);
      float cf[4] = {cr.x, cr.y, cr.z, cr.w};

      double val = HUGE_VAL; int idx = 0;
#pragma unroll
      for (int k = 0; k < 4; ++k) {
        if (!((usedmask >> k) & 1u)) {
          double cur = (double)cf[k] - ui - v[k];
          if (cur < minv[k]) { minv[k] = cur; way_sh[(lane << 2) + k + 1] = j0; }
          if (minv[k] < val) { val = minv[k]; idx = (lane << 2) + k + 1; }
        }
      }
      // 64-lane butterfly argmin, tie-break lowest index (matches np.argmin)
#pragma unroll
      for (int off = 32; off; off >>= 1) {
        double oval = __shfl_xor(val, off);
        int    oidx = __shfl_xor(idx, off);
        if (oval < val || (oval == val && oidx < idx)) { val = oval; idx = oidx; }
      }
      double delta = val; int j1 = idx;

#pragma unroll
      for (int k = 0; k < 4; ++k) {
        if ((usedmask >> k) & 1u) {
          int pm = p_sh[(lane << 2) + k + 1];   // distinct matched rows -> no collision
          u_sh[pm] += delta;
          v[k] -= delta;
        } else {
          minv[k] -= delta;
        }
      }
      if (lane == 0) u_sh[i] += delta;          // column 0 (p[0] = i) is always "used"

      j0 = j1;
      int pj = p_sh[j0];                        // p is constant during the search
      if (pj == 0) break;
      i0 = pj;
    }

    __syncthreads();                            // way writes -> augment reads
    if (lane == 0) {
      int jj = j0;
      while (jj) {
        int jn = way_sh[jj];
        p_sh[jj] = p_sh[jn];
        jj = jn;
      }
    }
    __syncthreads();                            // p writes -> next row reads
  }

  for (int j = lane + 1; j <= NPTS; j += 64)
    col_out[b * NPTS + (p_sh[j] - 1)] = j - 1;
}

// ---------------- reorder_1: out[b][d][n] = in[b][n][d] ----------------
__global__ __launch_bounds__(256) void transpose_kernel(const float* __restrict__ in,
                                                        float* __restrict__ out) {
  __shared__ float tile[32][33];
  const int b  = blockIdx.z;
  const int d0 = blockIdx.x * 32, n0 = blockIdx.y * 32;
  const int tx = threadIdx.x & 31, ty = threadIdx.x >> 5;
  const float* ip = in  + (size_t)b * NPTS * DIM;
  float*       op = out + (size_t)b * DIM * NPTS;
#pragma unroll
  for (int q = 0; q < 4; ++q)
    tile[ty + q * 8][tx] = ip[(size_t)(n0 + ty + q * 8) * DIM + d0 + tx];
  __syncthreads();
#pragma unroll
  for (int q = 0; q < 4; ++q)
    op[(size_t)(d0 + ty + q * 8) * NPTS + n0 + tx] = tile[tx][ty + q * 8];
}

// ---------------- reorder_2: out[b][d][n] = in[b][idx[b][n]][d] ----------------
__global__ __launch_bounds__(256) void gather_transpose_kernel(const float* __restrict__ in,
                                                               const int* __restrict__ idx,
                                                               float* __restrict__ out) {
  __shared__ float tile[32][33];
  __shared__ int   rows[32];
  const int b  = blockIdx.z;
  const int d0 = blockIdx.x * 32, n0 = blockIdx.y * 32;
  const int tx = threadIdx.x & 31, ty = threadIdx.x >> 5;
  if (threadIdx.x < 32) rows[threadIdx.x] = idx[b * NPTS + n0 + threadIdx.x];
  __syncthreads();
  const float* ip = in  + (size_t)b * NPTS * DIM;
  float*       op = out + (size_t)b * DIM * NPTS;
#pragma unroll
  for (int q = 0; q < 4; ++q)
    tile[ty + q * 8][tx] = ip[(size_t)rows[ty + q * 8] * DIM + d0 + tx];
  __syncthreads();
#pragma unroll
  for (int q = 0; q < 4; ++q)
    op[(size_t)(d0 + ty + q * 8) * NPTS + n0 + tx] = tile[tx][ty + q * 8];
}

extern "C" void kernel_launch(void* const* d_in, const int* in_sizes, int n_in,
                              void* d_out, int out_size, void* d_ws, size_t ws_size,
                              hipStream_t stream) {
  const float* seq1 = (const float*)d_in[0];
  const float* seq2 = (const float*)d_in[1];
  float* out1 = (float*)d_out;                          // [B, D, N]
  float* out2 = out1 + (size_t)BATCH * DIM * NPTS;      // [B, D, N]

  char*  ws     = (char*)d_ws;
  float* cost   = (float*)ws;                                    // 16 MiB
  float* sq1    = (float*)(ws + (size_t)BATCH * NPTS * NPTS * 4);
  float* sq2    = sq1 + BATCH * NPTS;
  int*   colidx = (int*)(sq2 + BATCH * NPTS);

  norms_kernel<<<BATCH * NPTS / 4, 256, 0, stream>>>(seq1, sq1);
  norms_kernel<<<BATCH * NPTS / 4, 256, 0, stream>>>(seq2, sq2);
  cost_kernel<<<dim3(NPTS / BN, NPTS / BM, BATCH), 256, 0, stream>>>(seq1, seq2, sq1, sq2, cost);
  hungarian_kernel<<<BATCH, 64, 0, stream>>>(cost, colidx);
  transpose_kernel<<<dim3(DIM / 32, NPTS / 32, BATCH), 256, 0, stream>>>(seq1, out1);
  gather_transpose_kernel<<<dim3(DIM / 32, NPTS / 32, BATCH), 256, 0, stream>>>(seq2, colidx, out2);
}

// Round 7
// 6571.689 us; speedup vs baseline: 1.5012x; 1.5012x over previous
//
#include <hip/hip_runtime.h>
#include <cstddef>
#include <cmath>

#define BATCH 64
#define NPTS  256
#define DIM   512

// ---------------- norms: out[r] = sum(x[r][:]^2), one wave per row ----------------
__global__ __launch_bounds__(256) void norms_kernel(const float* __restrict__ x,
                                                    float* __restrict__ out) {
  const int w = threadIdx.x >> 6, lane = threadIdx.x & 63;
  const int r = blockIdx.x * 4 + w;            // 4 waves/block, 1 row/wave
  const float4* row = reinterpret_cast<const float4*>(x + (size_t)r * DIM);
  float4 v0 = row[lane];
  float4 v1 = row[lane + 64];
  float s = v0.x*v0.x + v0.y*v0.y + v0.z*v0.z + v0.w*v0.w
          + v1.x*v1.x + v1.y*v1.y + v1.z*v1.z + v1.w*v1.w;
#pragma unroll
  for (int off = 32; off; off >>= 1) s += __shfl_xor(s, off);
  if (lane == 0) out[r] = s;
}

// ---------------- cost[b][j][i] = sqrt(max(sq2[j]+sq1[i]-2*<seq2_j,seq1_i>,0)) ----------------
#define BM 64
#define BN 64
#define BK 32
__global__ __launch_bounds__(256) void cost_kernel(const float* __restrict__ seq1,
                                                   const float* __restrict__ seq2,
                                                   const float* __restrict__ sq1,
                                                   const float* __restrict__ sq2,
                                                   float* __restrict__ cost) {
  const int b  = blockIdx.z;
  const int j0 = blockIdx.y * BM;   // rows  (seq2 index j)
  const int i0 = blockIdx.x * BN;   // cols  (seq1 index i)
  const int t  = threadIdx.x;
  const int tx = t & 15, ty = t >> 4;

  __shared__ float As[BK][BM + 1];  // seq2 tile, k-major
  __shared__ float Bs[BK][BN + 1];  // seq1 tile, k-major

  const float* A  = seq2 + ((size_t)b * NPTS + j0) * DIM;
  const float* Bp = seq1 + ((size_t)b * NPTS + i0) * DIM;

  float acc[4][4] = {};

  for (int k0 = 0; k0 < DIM; k0 += BK) {
#pragma unroll
    for (int l = 0; l < 2; ++l) {
      int f  = t + l * 256;           // 512 float4 loads per tile pair
      int r  = f >> 3;                // 0..63
      int c4 = (f & 7) * 4;           // 0..28
      float4 a  = *reinterpret_cast<const float4*>(A  + (size_t)r * DIM + k0 + c4);
      float4 bb = *reinterpret_cast<const float4*>(Bp + (size_t)r * DIM + k0 + c4);
      As[c4 + 0][r] = a.x;  As[c4 + 1][r] = a.y;  As[c4 + 2][r] = a.z;  As[c4 + 3][r] = a.w;
      Bs[c4 + 0][r] = bb.x; Bs[c4 + 1][r] = bb.y; Bs[c4 + 2][r] = bb.z; Bs[c4 + 3][r] = bb.w;
    }
    __syncthreads();
#pragma unroll
    for (int kk = 0; kk < BK; ++kk) {
      float a[4], bb[4];
#pragma unroll
      for (int q = 0; q < 4; ++q) a[q]  = As[kk][ty * 4 + q];
#pragma unroll
      for (int q = 0; q < 4; ++q) bb[q] = Bs[kk][tx * 4 + q];
#pragma unroll
      for (int x = 0; x < 4; ++x)
#pragma unroll
        for (int y = 0; y < 4; ++y) acc[x][y] += a[x] * bb[y];
    }
    __syncthreads();
  }

#pragma unroll
  for (int x = 0; x < 4; ++x) {
    int j = j0 + ty * 4 + x;
    float s2 = sq2[b * NPTS + j];
    float4 o;
    float r0 = s2 + sq1[b * NPTS + i0 + tx * 4 + 0] - 2.f * acc[x][0];
    float r1 = s2 + sq1[b * NPTS + i0 + tx * 4 + 1] - 2.f * acc[x][1];
    float r2 = s2 + sq1[b * NPTS + i0 + tx * 4 + 2] - 2.f * acc[x][2];
    float r3 = s2 + sq1[b * NPTS + i0 + tx * 4 + 3] - 2.f * acc[x][3];
    o.x = sqrtf(fmaxf(r0, 0.f)); o.y = sqrtf(fmaxf(r1, 0.f));
    o.z = sqrtf(fmaxf(r2, 0.f)); o.w = sqrtf(fmaxf(r3, 0.f));
    *reinterpret_cast<float4*>(cost + ((size_t)b * NPTS + j) * NPTS + i0 + tx * 4) = o;
  }
}

// ---------------- Hungarian — one wave per batch problem ----------------
// Exact successive-shortest-path (JV) with a column-reduction warm start.
// Optimal assignment is a.s. unique for random data, so ANY exact solver
// matches the reference. f64 duals keep arithmetic error ~1e-13 << optimum gap.
// Warm start validity: u=0, v[j]=min_i c[i,j], matching = {(argmin row, j)}
// claimed uniquely -> reduced costs >= 0, matched pairs == 0 (compl. slackness).
// HARDENED (R6 post-mortem): every theoretically-unreachable abnormal path is
// guarded so a latent bug shows as wrong output (absmax), never a GPU fault.
__global__ __launch_bounds__(64) void hungarian_kernel(const float* __restrict__ cost,
                                                       int* __restrict__ col_out) {
  const int b    = blockIdx.x;
  const int lane = threadIdx.x;                 // owns columns c0..c0+3 (0-based)
  const int c0   = lane * 4;
  const float* C = cost + (size_t)b * NPTS * NPTS;

  __shared__ double u_sh[NPTS + 1];
  __shared__ int    p_sh[NPTS + 1];     // p[j] = row matched to column j (1-based)
  __shared__ int    way_sh[NPTS + 1];
  __shared__ int    rowclaim[NPTS];     // row -> claiming column, or -1
  __shared__ int    freerows[NPTS];
  __shared__ int    nfree_sh;

  for (int t = lane; t <= NPTS; t += 64) { u_sh[t] = 0.0; p_sh[t] = 0; way_sh[t] = 0; }
  for (int t = lane; t < NPTS; t += 64) rowclaim[t] = -1;
  if (lane == 0) nfree_sh = 0;
  __syncthreads();

  // ---- column reduction: v[j] = min_i c[i][j] (argmin row per column) ----
  float vm0 = INFINITY, vm1 = INFINITY, vm2 = INFINITY, vm3 = INFINITY;
  int   bi0 = 0, bi1 = 0, bi2 = 0, bi3 = 0;
#pragma unroll 4
  for (int i = 0; i < NPTS; ++i) {
    float4 cr = *reinterpret_cast<const float4*>(C + (size_t)i * NPTS + c0);
    if (cr.x < vm0) { vm0 = cr.x; bi0 = i; }
    if (cr.y < vm1) { vm1 = cr.y; bi1 = i; }
    if (cr.z < vm2) { vm2 = cr.z; bi2 = i; }
    if (cr.w < vm3) { vm3 = cr.w; bi3 = i; }
  }
  double v[4] = { (double)vm0, (double)vm1, (double)vm2, (double)vm3 };

  // claim argmin rows (any winner is CS-valid); losers' columns stay unmatched
  int got0 = atomicCAS(&rowclaim[bi0], -1, c0 + 0);
  int got1 = atomicCAS(&rowclaim[bi1], -1, c0 + 1);
  int got2 = atomicCAS(&rowclaim[bi2], -1, c0 + 2);
  int got3 = atomicCAS(&rowclaim[bi3], -1, c0 + 3);
  p_sh[c0 + 1] = (got0 == -1) ? bi0 + 1 : 0;
  p_sh[c0 + 2] = (got1 == -1) ? bi1 + 1 : 0;
  p_sh[c0 + 3] = (got2 == -1) ? bi2 + 1 : 0;
  p_sh[c0 + 4] = (got3 == -1) ? bi3 + 1 : 0;
  __syncthreads();

  // unclaimed rows need augmentation
#pragma unroll
  for (int k = 0; k < 4; ++k) {
    int r = c0 + k;
    if (rowclaim[r] == -1) { int s = atomicAdd(&nfree_sh, 1); freerows[s] = r + 1; }
  }
  __syncthreads();
  const int nfree = nfree_sh;

  // per-lane register mirror of p for owned columns (p constant during a search)
  int pr0 = p_sh[c0 + 1], pr1 = p_sh[c0 + 2], pr2 = p_sh[c0 + 3], pr3 = p_sh[c0 + 4];

  for (int fi = 0; fi < nfree; ++fi) {
    const int i = freerows[fi];
    if (lane == 0) p_sh[0] = i;
    double minv[4] = { HUGE_VAL, HUGE_VAL, HUGE_VAL, HUGE_VAL };
    unsigned usedmask = 0;
    int j0 = 0, i0 = i;

    for (int it = 0; it <= NPTS; ++it) {        // bounded: each iter marks a new column
      if (j0 > 0) {
        int c = j0 - 1;
        if ((c >> 2) == lane) usedmask |= 1u << (c & 3);
      }
      double ui = u_sh[i0];
      float4 cr = *reinterpret_cast<const float4*>(C + (size_t)(i0 - 1) * NPTS + c0);
      float cf[4] = { cr.x, cr.y, cr.z, cr.w };

      double val = HUGE_VAL; int idx = 0;
#pragma unroll
      for (int k = 0; k < 4; ++k) {
        if (!((usedmask >> k) & 1u)) {
          double cur = (double)cf[k] - ui - v[k];
          if (cur < minv[k]) { minv[k] = cur; way_sh[c0 + k + 1] = j0; }
          if (minv[k] < val) { val = minv[k]; idx = c0 + k + 1; }
        }
      }
      // 64-lane butterfly argmin (tie-break lowest index -> deterministic)
#pragma unroll
      for (int off = 32; off; off >>= 1) {
        double oval = __shfl_xor(val, off);
        int    oidx = __shfl_xor(idx, off);
        if (oval < val || (oval == val && oidx < idx)) { val = oval; idx = oidx; }
      }
      const double delta = val; const int j1 = idx;
      if (j1 == 0) { j0 = 0; break; }           // GUARD: unreachable in exact math

#pragma unroll
      for (int k = 0; k < 4; ++k) {
        if ((usedmask >> k) & 1u) {
          int pm = (k == 0) ? pr0 : (k == 1) ? pr1 : (k == 2) ? pr2 : pr3;
          u_sh[pm] += delta;                    // distinct matched rows: no collision
          v[k] -= delta;
        } else {
          minv[k] -= delta;
        }
      }
      if (lane == 0) u_sh[i] += delta;          // virtual column 0 (p[0] = i)

      j0 = j1;
      // p[j1] from the register mirror: uniform (ksel, src) -> select + 1 shuffle
      int ksel = (j1 - 1) & 3, src = (j1 - 1) >> 2;
      int cand = pr0;
      cand = (ksel == 1) ? pr1 : cand;
      cand = (ksel == 2) ? pr2 : cand;
      cand = (ksel == 3) ? pr3 : cand;
      int pj = __shfl(cand, src);
      if (pj == 0) break;
      i0 = pj;
    }

    __syncthreads();                            // way/minv writes -> augment reads
    if (lane == 0) {
      int jj = j0;
      for (int guard = 0; jj && guard <= NPTS; ++guard) {   // GUARD: bounded walk
        int jn = way_sh[jj];
        p_sh[jj] = p_sh[jn];
        jj = jn;
      }
    }
    __syncthreads();                            // p writes -> mirror reload
    pr0 = p_sh[c0 + 1]; pr1 = p_sh[c0 + 2]; pr2 = p_sh[c0 + 3]; pr3 = p_sh[c0 + 4];
  }

  __syncthreads();
  // GUARD: clamp destination into [0, NPTS); identity fallback for unmatched j.
  for (int j = lane + 1; j <= NPTS; j += 64) {
    int pj  = p_sh[j];
    int dst = (pj >= 1 && pj <= NPTS) ? pj - 1 : j - 1;
    col_out[b * NPTS + dst] = j - 1;
  }
}

// ---------------- reorder_1: out[b][d][n] = in[b][n][d] ----------------
__global__ __launch_bounds__(256) void transpose_kernel(const float* __restrict__ in,
                                                        float* __restrict__ out) {
  __shared__ float tile[32][33];
  const int b  = blockIdx.z;
  const int d0 = blockIdx.x * 32, n0 = blockIdx.y * 32;
  const int tx = threadIdx.x & 31, ty = threadIdx.x >> 5;
  const float* ip = in  + (size_t)b * NPTS * DIM;
  float*       op = out + (size_t)b * DIM * NPTS;
#pragma unroll
  for (int q = 0; q < 4; ++q)
    tile[ty + q * 8][tx] = ip[(size_t)(n0 + ty + q * 8) * DIM + d0 + tx];
  __syncthreads();
#pragma unroll
  for (int q = 0; q < 4; ++q)
    op[(size_t)(d0 + ty + q * 8) * NPTS + n0 + tx] = tile[tx][ty + q * 8];
}

// ---------------- reorder_2: out[b][d][n] = in[b][idx[b][n]][d] ----------------
__global__ __launch_bounds__(256) void gather_transpose_kernel(const float* __restrict__ in,
                                                               const int* __restrict__ idx,
                                                               float* __restrict__ out) {
  __shared__ float tile[32][33];
  __shared__ int   rows[32];
  const int b  = blockIdx.z;
  const int d0 = blockIdx.x * 32, n0 = blockIdx.y * 32;
  const int tx = threadIdx.x & 31, ty = threadIdx.x >> 5;
  if (threadIdx.x < 32) {
    int r = idx[b * NPTS + n0 + threadIdx.x];
    rows[threadIdx.x] = ((unsigned)r < NPTS) ? r : 0;   // GUARD: never deref poison
  }
  __syncthreads();
  const float* ip = in  + (size_t)b * NPTS * DIM;
  float*       op = out + (size_t)b * DIM * NPTS;
#pragma unroll
  for (int q = 0; q < 4; ++q)
    tile[ty + q * 8][tx] = ip[(size_t)rows[ty + q * 8] * DIM + d0 + tx];
  __syncthreads();
#pragma unroll
  for (int q = 0; q < 4; ++q)
    op[(size_t)(d0 + ty + q * 8) * NPTS + n0 + tx] = tile[tx][ty + q * 8];
}

extern "C" void kernel_launch(void* const* d_in, const int* in_sizes, int n_in,
                              void* d_out, int out_size, void* d_ws, size_t ws_size,
                              hipStream_t stream) {
  const float* seq1 = (const float*)d_in[0];
  const float* seq2 = (const float*)d_in[1];
  float* out1 = (float*)d_out;                          // [B, D, N]
  float* out2 = out1 + (size_t)BATCH * DIM * NPTS;      // [B, D, N]

  char*  ws     = (char*)d_ws;
  float* cost   = (float*)ws;                                    // 16 MiB
  float* sq1    = (float*)(ws + (size_t)BATCH * NPTS * NPTS * 4);
  float* sq2    = sq1 + BATCH * NPTS;
  int*   colidx = (int*)(sq2 + BATCH * NPTS);

  norms_kernel<<<BATCH * NPTS / 4, 256, 0, stream>>>(seq1, sq1);
  norms_kernel<<<BATCH * NPTS / 4, 256, 0, stream>>>(seq2, sq2);
  cost_kernel<<<dim3(NPTS / BN, NPTS / BM, BATCH), 256, 0, stream>>>(seq1, seq2, sq1, sq2, cost);
  hungarian_kernel<<<BATCH, 64, 0, stream>>>(cost, colidx);
  transpose_kernel<<<dim3(DIM / 32, NPTS / 32, BATCH), 256, 0, stream>>>(seq1, out1);
  gather_transpose_kernel<<<dim3(DIM / 32, NPTS / 32, BATCH), 256, 0, stream>>>(seq2, colidx, out2);
}

// Round 8
// 5482.501 us; speedup vs baseline: 1.7994x; 1.1987x over previous
//
#include <hip/hip_runtime.h>
#include <cstddef>
#include <cmath>

#define BATCH 64
#define NPTS  256
#define DIM   512

// ---------------- norms: out[r] = sum(x[r][:]^2), one wave per row ----------------
__global__ __launch_bounds__(256) void norms_kernel(const float* __restrict__ x,
                                                    float* __restrict__ out) {
  const int w = threadIdx.x >> 6, lane = threadIdx.x & 63;
  const int r = blockIdx.x * 4 + w;            // 4 waves/block, 1 row/wave
  const float4* row = reinterpret_cast<const float4*>(x + (size_t)r * DIM);
  float4 v0 = row[lane];
  float4 v1 = row[lane + 64];
  float s = v0.x*v0.x + v0.y*v0.y + v0.z*v0.z + v0.w*v0.w
          + v1.x*v1.x + v1.y*v1.y + v1.z*v1.z + v1.w*v1.w;
#pragma unroll
  for (int off = 32; off; off >>= 1) s += __shfl_xor(s, off);
  if (lane == 0) out[r] = s;
}

// ---------------- cost[b][j][i] = sqrt(max(sq2[j]+sq1[i]-2*<seq2_j,seq1_i>,0)) ----------------
#define BM 64
#define BN 64
#define BK 32
__global__ __launch_bounds__(256) void cost_kernel(const float* __restrict__ seq1,
                                                   const float* __restrict__ seq2,
                                                   const float* __restrict__ sq1,
                                                   const float* __restrict__ sq2,
                                                   float* __restrict__ cost) {
  const int b  = blockIdx.z;
  const int j0 = blockIdx.y * BM;   // rows  (seq2 index j)
  const int i0 = blockIdx.x * BN;   // cols  (seq1 index i)
  const int t  = threadIdx.x;
  const int tx = t & 15, ty = t >> 4;

  __shared__ float As[BK][BM + 1];  // seq2 tile, k-major
  __shared__ float Bs[BK][BN + 1];  // seq1 tile, k-major

  const float* A  = seq2 + ((size_t)b * NPTS + j0) * DIM;
  const float* Bp = seq1 + ((size_t)b * NPTS + i0) * DIM;

  float acc[4][4] = {};

  for (int k0 = 0; k0 < DIM; k0 += BK) {
#pragma unroll
    for (int l = 0; l < 2; ++l) {
      int f  = t + l * 256;           // 512 float4 loads per tile pair
      int r  = f >> 3;                // 0..63
      int c4 = (f & 7) * 4;           // 0..28
      float4 a  = *reinterpret_cast<const float4*>(A  + (size_t)r * DIM + k0 + c4);
      float4 bb = *reinterpret_cast<const float4*>(Bp + (size_t)r * DIM + k0 + c4);
      As[c4 + 0][r] = a.x;  As[c4 + 1][r] = a.y;  As[c4 + 2][r] = a.z;  As[c4 + 3][r] = a.w;
      Bs[c4 + 0][r] = bb.x; Bs[c4 + 1][r] = bb.y; Bs[c4 + 2][r] = bb.z; Bs[c4 + 3][r] = bb.w;
    }
    __syncthreads();
#pragma unroll
    for (int kk = 0; kk < BK; ++kk) {
      float a[4], bb[4];
#pragma unroll
      for (int q = 0; q < 4; ++q) a[q]  = As[kk][ty * 4 + q];
#pragma unroll
      for (int q = 0; q < 4; ++q) bb[q] = Bs[kk][tx * 4 + q];
#pragma unroll
      for (int x = 0; x < 4; ++x)
#pragma unroll
        for (int y = 0; y < 4; ++y) acc[x][y] += a[x] * bb[y];
    }
    __syncthreads();
  }

#pragma unroll
  for (int x = 0; x < 4; ++x) {
    int j = j0 + ty * 4 + x;
    float s2 = sq2[b * NPTS + j];
    float4 o;
    float r0 = s2 + sq1[b * NPTS + i0 + tx * 4 + 0] - 2.f * acc[x][0];
    float r1 = s2 + sq1[b * NPTS + i0 + tx * 4 + 1] - 2.f * acc[x][1];
    float r2 = s2 + sq1[b * NPTS + i0 + tx * 4 + 2] - 2.f * acc[x][2];
    float r3 = s2 + sq1[b * NPTS + i0 + tx * 4 + 3] - 2.f * acc[x][3];
    o.x = sqrtf(fmaxf(r0, 0.f)); o.y = sqrtf(fmaxf(r1, 0.f));
    o.z = sqrtf(fmaxf(r2, 0.f)); o.w = sqrtf(fmaxf(r3, 0.f));
    *reinterpret_cast<float4*>(cost + ((size_t)b * NPTS + j) * NPTS + i0 + tx * 4) = o;
  }
}

// ---------------- Hungarian — one wave per batch problem, ALL-REGISTER inner loop ----
// Exact successive-shortest-path (JV) + column-reduction warm start.
// u is never stored: complementary slackness gives u[i0] = C[i0][j0] - v[j0],
// where the owning lane has both C[i0][j0] (just-loaded) and v[j0] (register).
// p[] and way[] live in registers (4/lane), looked up via uniform select+shfl.
// The Dijkstra inner loop performs ZERO LDS accesses.
// f64 duals: arithmetic error ~1e-13 << optimum gap (a.s. unique optimum).
// HARDENED: abnormal paths degrade to wrong output (absmax), never a GPU fault.
__global__ __launch_bounds__(64) void hungarian_kernel(const float* __restrict__ cost,
                                                       int* __restrict__ col_out) {
  const int b    = blockIdx.x;
  const int lane = threadIdx.x;                 // owns 0-based columns c0..c0+3
  const int c0   = lane * 4;
  const float* C = cost + (size_t)b * NPTS * NPTS;

  __shared__ int rowclaim[NPTS];                // setup only
  __shared__ int freerows[NPTS];
  __shared__ int nfree_sh;

  for (int t = lane; t < NPTS; t += 64) rowclaim[t] = -1;
  if (lane == 0) nfree_sh = 0;
  __syncthreads();

  // ---- column reduction: v[j] = min_i c[i][j], remember argmin row ----
  float vm[4] = {INFINITY, INFINITY, INFINITY, INFINITY};
  int   bi[4] = {0, 0, 0, 0};
#pragma unroll 4
  for (int i = 0; i < NPTS; ++i) {
    float4 cr = *reinterpret_cast<const float4*>(C + (size_t)i * NPTS + c0);
    float cf[4] = {cr.x, cr.y, cr.z, cr.w};
#pragma unroll
    for (int k = 0; k < 4; ++k)
      if (cf[k] < vm[k]) { vm[k] = cf[k]; bi[k] = i; }
  }
  double v[4];
  int    pr[4];                                 // p for owned columns (1-based row, 0=free)
#pragma unroll
  for (int k = 0; k < 4; ++k) v[k] = (double)vm[k];

  // claim argmin rows (atomicCAS winner is CS-valid: c - 0 - v = 0)
#pragma unroll
  for (int k = 0; k < 4; ++k) {
    int got = atomicCAS(&rowclaim[bi[k]], -1, c0 + k);
    pr[k] = (got == -1) ? bi[k] + 1 : 0;
  }
  __syncthreads();
#pragma unroll
  for (int k = 0; k < 4; ++k) {
    int r = c0 + k;
    if (rowclaim[r] == -1) { int s = atomicAdd(&nfree_sh, 1); freerows[s] = r + 1; }
  }
  __syncthreads();
  const int nfree = nfree_sh;

  for (int fi = 0; fi < nfree; ++fi) {
    const int i = freerows[fi];                 // uniform LDS broadcast (outside hot loop)
    double minv[4] = {HUGE_VAL, HUGE_VAL, HUGE_VAL, HUGE_VAL};
    int    way[4]  = {0, 0, 0, 0};
    unsigned usedmask = 0;
    int j0 = 0, i0 = i;

    for (int it = 0; it <= NPTS; ++it) {        // bounded: each iter marks a new column
      const int ksel = (j0 - 1) & 3, src = (j0 - 1) >> 2;  // valid only when j0>0
      if (j0 > 0 && src == lane) usedmask |= 1u << ksel;

      float4 cr = *reinterpret_cast<const float4*>(C + (size_t)(i0 - 1) * NPTS + c0);
      float cf[4] = {cr.x, cr.y, cr.z, cr.w};

      // u[i0] derived from complementary slackness (no LDS)
      double u_i0 = 0.0;
      if (j0 > 0) {
        double cand = (double)cf[ksel] - v[ksel];
        u_i0 = __shfl(cand, src);
      }

      double val = HUGE_VAL; int idx = 0;
#pragma unroll
      for (int k = 0; k < 4; ++k) {
        if (!((usedmask >> k) & 1u)) {
          double cur = (double)cf[k] - u_i0 - v[k];
          if (cur < minv[k]) { minv[k] = cur; way[k] = j0; }
          if (minv[k] < val) { val = minv[k]; idx = c0 + k + 1; }
        }
      }
      // 64-lane butterfly argmin (tie-break lowest index -> deterministic)
#pragma unroll
      for (int off = 32; off; off >>= 1) {
        double oval = __shfl_xor(val, off);
        int    oidx = __shfl_xor(idx, off);
        if (oval < val || (oval == val && oidx < idx)) { val = oval; idx = oidx; }
      }
      const double delta = val; const int j1 = idx;
      if (j1 == 0) { j0 = 0; break; }           // GUARD: unreachable in exact math

      // dual update: pure registers (u update is implicit via derived-u)
#pragma unroll
      for (int k = 0; k < 4; ++k) {
        if ((usedmask >> k) & 1u) v[k] -= delta; else minv[k] -= delta;
      }

      j0 = j1;
      // p[j1]: uniform select + shuffle
      int ks = (j1 - 1) & 3, sr = (j1 - 1) >> 2;
      int cand = pr[0];
      cand = (ks == 1) ? pr[1] : cand;
      cand = (ks == 2) ? pr[2] : cand;
      cand = (ks == 3) ? pr[3] : cand;
      int pj = __shfl(cand, sr);
      if (pj == 0) break;                       // augmenting path found
      i0 = pj;
    }

    // ---- augment: wave-uniform register walk (p[jj] = p[way[jj]], p[0] = i) ----
    int jj = j0;
    for (int guard = 0; jj && guard <= NPTS; ++guard) {   // GUARD: bounded walk
      int ks = (jj - 1) & 3, sr = (jj - 1) >> 2;
      int wc = way[0];
      wc = (ks == 1) ? way[1] : wc;
      wc = (ks == 2) ? way[2] : wc;
      wc = (ks == 3) ? way[3] : wc;
      int jn = __shfl(wc, sr);                  // jn uniform (sr uniform)
      int pv;
      if (jn == 0) {
        pv = i;
      } else {
        int ks2 = (jn - 1) & 3, sr2 = (jn - 1) >> 2;
        int pc = pr[0];
        pc = (ks2 == 1) ? pr[1] : pc;
        pc = (ks2 == 2) ? pr[2] : pc;
        pc = (ks2 == 3) ? pr[3] : pc;
        pv = __shfl(pc, sr2);
      }
      if (sr == lane) pr[ks] = pv;              // owner updates its register
      jj = jn;
    }
  }

  // ---- output: each lane writes its 4 owned columns ----
  // GUARD: clamp destination; identity fallback for (unreachable) unmatched j.
#pragma unroll
  for (int k = 0; k < 4; ++k) {
    int pj  = pr[k];
    int dst = (pj >= 1 && pj <= NPTS) ? pj - 1 : c0 + k;
    col_out[b * NPTS + dst] = c0 + k;
  }
}

// ---------------- reorder_1: out[b][d][n] = in[b][n][d] ----------------
__global__ __launch_bounds__(256) void transpose_kernel(const float* __restrict__ in,
                                                        float* __restrict__ out) {
  __shared__ float tile[32][33];
  const int b  = blockIdx.z;
  const int d0 = blockIdx.x * 32, n0 = blockIdx.y * 32;
  const int tx = threadIdx.x & 31, ty = threadIdx.x >> 5;
  const float* ip = in  + (size_t)b * NPTS * DIM;
  float*       op = out + (size_t)b * DIM * NPTS;
#pragma unroll
  for (int q = 0; q < 4; ++q)
    tile[ty + q * 8][tx] = ip[(size_t)(n0 + ty + q * 8) * DIM + d0 + tx];
  __syncthreads();
#pragma unroll
  for (int q = 0; q < 4; ++q)
    op[(size_t)(d0 + ty + q * 8) * NPTS + n0 + tx] = tile[tx][ty + q * 8];
}

// ---------------- reorder_2: out[b][d][n] = in[b][idx[b][n]][d] ----------------
__global__ __launch_bounds__(256) void gather_transpose_kernel(const float* __restrict__ in,
                                                               const int* __restrict__ idx,
                                                               float* __restrict__ out) {
  __shared__ float tile[32][33];
  __shared__ int   rows[32];
  const int b  = blockIdx.z;
  const int d0 = blockIdx.x * 32, n0 = blockIdx.y * 32;
  const int tx = threadIdx.x & 31, ty = threadIdx.x >> 5;
  if (threadIdx.x < 32) {
    int r = idx[b * NPTS + n0 + threadIdx.x];
    rows[threadIdx.x] = ((unsigned)r < NPTS) ? r : 0;   // GUARD: never deref poison
  }
  __syncthreads();
  const float* ip = in  + (size_t)b * NPTS * DIM;
  float*       op = out + (size_t)b * DIM * NPTS;
#pragma unroll
  for (int q = 0; q < 4; ++q)
    tile[ty + q * 8][tx] = ip[(size_t)rows[ty + q * 8] * DIM + d0 + tx];
  __syncthreads();
#pragma unroll
  for (int q = 0; q < 4; ++q)
    op[(size_t)(d0 + ty + q * 8) * NPTS + n0 + tx] = tile[tx][ty + q * 8];
}

extern "C" void kernel_launch(void* const* d_in, const int* in_sizes, int n_in,
                              void* d_out, int out_size, void* d_ws, size_t ws_size,
                              hipStream_t stream) {
  const float* seq1 = (const float*)d_in[0];
  const float* seq2 = (const float*)d_in[1];
  float* out1 = (float*)d_out;                          // [B, D, N]
  float* out2 = out1 + (size_t)BATCH * DIM * NPTS;      // [B, D, N]

  char*  ws     = (char*)d_ws;
  float* cost   = (float*)ws;                                    // 16 MiB
  float* sq1    = (float*)(ws + (size_t)BATCH * NPTS * NPTS * 4);
  float* sq2    = sq1 + BATCH * NPTS;
  int*   colidx = (int*)(sq2 + BATCH * NPTS);

  norms_kernel<<<BATCH * NPTS / 4, 256, 0, stream>>>(seq1, sq1);
  norms_kernel<<<BATCH * NPTS / 4, 256, 0, stream>>>(seq2, sq2);
  cost_kernel<<<dim3(NPTS / BN, NPTS / BM, BATCH), 256, 0, stream>>>(seq1, seq2, sq1, sq2, cost);
  hungarian_kernel<<<BATCH, 64, 0, stream>>>(cost, colidx);
  transpose_kernel<<<dim3(DIM / 32, NPTS / 32, BATCH), 256, 0, stream>>>(seq1, out1);
  gather_transpose_kernel<<<dim3(DIM / 32, NPTS / 32, BATCH), 256, 0, stream>>>(seq2, colidx, out2);
}